// Round 2
// baseline (131.282 us; speedup 1.0000x reference)
//
#include <hip/hip_runtime.h>
#include <math.h>

// Problem constants (fixed by setup_inputs): B=2, S=2048, D=128, NH=8, NB=32
constexpr int B = 2;
constexpr int S = 2048;
constexpr int D = 128;
constexpr int NH = 8;
constexpr int NK = 16;          // num_buckets / 2
constexpr int NB = 32;          // num_buckets
constexpr float EPS = 1e-5f;
constexpr float SCALE = 0.08838834764831845f;  // 1/sqrt(128)

// ---------------------------------------------------------------------------
// K1: LayerNorm + last-round LSH hash, one WAVE per row, zero barriers.
// Lane l holds x[row, l] and x[row, l+64].
// ---------------------------------------------------------------------------
__global__ __launch_bounds__(256) void ln_hash_kernel(
    const float* __restrict__ x, const float* __restrict__ mask,
    const float* __restrict__ rot, float* __restrict__ xm,
    int* __restrict__ bucket, int* __restrict__ counts)
{
    const int wave = threadIdx.x >> 6;
    const int lane = threadIdx.x & 63;
    const int row  = blockIdx.x * 4 + wave;       // grid = B*S/4 blocks
    const int b    = row >> 11;                   // row / S

    const float v0 = x[(size_t)row * D + lane];
    const float v1 = x[(size_t)row * D + lane + 64];

    float s = v0 + v1;
    #pragma unroll
    for (int off = 32; off > 0; off >>= 1) s += __shfl_xor(s, off, 64);
    const float mu = s * (1.0f / 128.0f);

    const float c0 = v0 - mu, c1 = v1 - mu;
    float s2 = c0 * c0 + c1 * c1;
    #pragma unroll
    for (int off = 32; off > 0; off >>= 1) s2 += __shfl_xor(s2, off, 64);
    const float rstd = 1.0f / sqrtf(s2 * (1.0f / 128.0f) + EPS);

    const float xn0 = c0 * rstd, xn1 = c1 * rstd;
    const float mk = mask[row];
    xm[(size_t)row * D + lane]      = xn0 * mk;
    xm[(size_t)row * D + lane + 64] = xn1 * mk;

    // projection (last hash round only): rot[k] = sum_d xn[d]*R[b,d,NH-1,k]
    // R row for d: 16 contiguous floats at rot + ((b*D+d)*NH + 7)*NK
    const float* r0 = rot + (((size_t)(b * D + lane)) * NH + (NH - 1)) * NK;
    const float* r1 = rot + (((size_t)(b * D + lane + 64)) * NH + (NH - 1)) * NK;
    float racc[NK];
    #pragma unroll
    for (int k = 0; k < NK; ++k) racc[k] = xn0 * r0[k] + xn1 * r1[k];
    #pragma unroll
    for (int k = 0; k < NK; ++k) {
        float t = racc[k];
        #pragma unroll
        for (int off = 32; off > 0; off >>= 1) t += __shfl_xor(t, off, 64);
        racc[k] = t;                              // all lanes hold full sum
    }

    // argmax over [rot, -rot], first-max semantics (redundant on all lanes)
    float best = racc[0]; int bi = 0;
    #pragma unroll
    for (int k = 1; k < NK; ++k) if (racc[k] > best) { best = racc[k]; bi = k; }
    #pragma unroll
    for (int k = 0; k < NK; ++k) if (-racc[k] > best) { best = -racc[k]; bi = k + NK; }

    if (lane == 0) {
        bucket[row] = bi;
        atomicAdd(&counts[b * NB + bi], 1);
    }
}

// ---------------------------------------------------------------------------
// K2: per-batch exclusive prefix sum over 32 bucket counts (tiny).
// ---------------------------------------------------------------------------
__global__ void prefix_kernel(const int* __restrict__ counts,
                              int* __restrict__ offsets,
                              int* __restrict__ cursors)
{
    const int b = threadIdx.x;
    if (b < B) {
        int run = 0;
        for (int k = 0; k < NB; ++k) {
            offsets[b * NB + k] = run;
            cursors[b * NB + k] = run;
            run += counts[b * NB + k];
        }
    }
}

// ---------------------------------------------------------------------------
// K3: scatter rows into bucket-sorted permutation. One thread per row.
// ---------------------------------------------------------------------------
__global__ __launch_bounds__(256) void scatter_kernel(
    const int* __restrict__ bucket, int* __restrict__ cursors,
    int* __restrict__ perm)
{
    const int row = blockIdx.x * 256 + threadIdx.x;   // grid = B*S/256
    const int b = row >> 11;
    const int beta = bucket[row];
    const int pl = atomicAdd(&cursors[b * NB + beta], 1);
    perm[b * S + pl] = row;                           // order within bucket irrelevant
}

// ---------------------------------------------------------------------------
// K4: per-query bucketed attention. One block (256 thr) per sorted position.
// Exact reference softmax: zero scores for out-of-bucket keys contribute
// (S - n) * exp(-M) to the denominator.
// ---------------------------------------------------------------------------
__global__ __launch_bounds__(256) void attn_kernel(
    const float* __restrict__ xm, const int* __restrict__ perm,
    const int* __restrict__ bucket, const int* __restrict__ offsets,
    const int* __restrict__ counts, float* __restrict__ out)
{
    const int p    = blockIdx.x;          // sorted position, b*S + local
    const int b    = p >> 11;
    const int tid  = threadIdx.x;
    const int lane = tid & 63;
    const int wave = tid >> 6;
    const int h    = lane >> 5;           // half-wave (2 keys per wave)
    const int sub  = lane & 31;

    __shared__ float w[S];                // scores -> exp weights
    __shared__ int   idx[S];              // key row indices
    __shared__ float part[4];
    __shared__ float bc;
    __shared__ int   hdr[4];
    __shared__ float red2[256];

    if (tid == 0) {
        const int row  = perm[p];
        const int beta = bucket[row];
        hdr[0] = row;
        hdr[1] = offsets[b * NB + beta];
        hdr[2] = counts[b * NB + beta];
    }
    __syncthreads();
    const int row = hdr[0];
    const int lo  = hdr[1];
    const int n   = hdr[2];

    for (int i = tid; i < n; i += 256) idx[i] = perm[b * S + lo + i];

    // query fragment: 32 lanes cover 128 floats as float4
    const float4 qf = *(const float4*)(xm + (size_t)row * D + sub * 4);
    __syncthreads();

    // dots: 8 keys per loop trip (4 waves x 2 half-waves)
    for (int i = wave * 2 + h; i < n; i += 8) {
        const float4 kf = *(const float4*)(xm + (size_t)idx[i] * D + sub * 4);
        float d = qf.x * kf.x + qf.y * kf.y + qf.z * kf.z + qf.w * kf.w;
        d += __shfl_xor(d, 16, 64);
        d += __shfl_xor(d, 8, 64);
        d += __shfl_xor(d, 4, 64);
        d += __shfl_xor(d, 2, 64);
        d += __shfl_xor(d, 1, 64);
        if (sub == 0) w[i] = d * SCALE;
    }
    __syncthreads();

    // max over scores; S-n zero entries floor it at 0
    float m = 0.0f;
    for (int i = tid; i < n; i += 256) m = fmaxf(m, w[i]);
    #pragma unroll
    for (int off = 32; off > 0; off >>= 1) m = fmaxf(m, __shfl_xor(m, off, 64));
    if (lane == 0) part[wave] = m;
    __syncthreads();
    if (tid == 0) bc = fmaxf(fmaxf(part[0], part[1]), fmaxf(part[2], part[3]));
    __syncthreads();
    const float M = bc;

    // exp in place + denominator (with zero-score correction)
    float dsum = 0.0f;
    for (int i = tid; i < n; i += 256) {
        const float e = expf(w[i] - M);
        w[i] = e;
        dsum += e;
    }
    #pragma unroll
    for (int off = 32; off > 0; off >>= 1) dsum += __shfl_xor(dsum, off, 64);
    if (lane == 0) part[wave] = dsum;
    __syncthreads();
    if (tid == 0)
        bc = part[0] + part[1] + part[2] + part[3] + (float)(S - n) * expf(-M);
    __syncthreads();
    const float inv = 1.0f / bc;

    // output: out_d = inv * sum_i w[i] * xm[idx[i]][d]; 2 halves x 128 dims
    const int d    = tid & 127;
    const int half = tid >> 7;
    float acc = 0.0f;
    for (int i = half; i < n; i += 2)
        acc += w[i] * xm[(size_t)idx[i] * D + d];
    red2[tid] = acc;
    __syncthreads();
    if (tid < 128)
        out[(size_t)row * D + tid] = inv * (red2[tid] + red2[tid + 128]);
}

// ---------------------------------------------------------------------------
extern "C" void kernel_launch(void* const* d_in, const int* in_sizes, int n_in,
                              void* d_out, int out_size, void* d_ws, size_t ws_size,
                              hipStream_t stream) {
    const float* x    = (const float*)d_in[0];   // (B,S,D) fp32
    const float* mask = (const float*)d_in[1];   // (B,S) fp32
    const float* rot  = (const float*)d_in[2];   // (B,D,NH,NK) fp32

    char* ws = (char*)d_ws;
    float* xm     = (float*)ws;                          ws += (size_t)B * S * D * sizeof(float); // 2 MB
    int*   bucket = (int*)ws;                            ws += (size_t)B * S * sizeof(int);       // 16 KB
    int*   perm   = (int*)ws;                            ws += (size_t)B * S * sizeof(int);       // 16 KB
    int*   counts = (int*)ws;                            ws += B * NB * sizeof(int);
    int*   offsets= (int*)ws;                            ws += B * NB * sizeof(int);
    int*   cursors= (int*)ws;
    float* out    = (float*)d_out;

    hipMemsetAsync(counts, 0, B * NB * sizeof(int), stream);
    ln_hash_kernel<<<B * S / 4, 256, 0, stream>>>(x, mask, rot, xm, bucket, counts);
    prefix_kernel<<<1, 64, 0, stream>>>(counts, offsets, cursors);
    scatter_kernel<<<B * S / 256, 256, 0, stream>>>(bucket, cursors, perm);
    attn_kernel<<<B * S, 256, 0, stream>>>(xm, perm, bucket, offsets, counts, out);
}

// Round 4
// 79.114 us; speedup vs baseline: 1.6594x; 1.6594x over previous
//
#include <hip/hip_runtime.h>
#include <math.h>

// Problem constants (fixed by setup_inputs): B=2, S=2048, D=128, NH=8, NB=32
constexpr int B = 2;
constexpr int S = 2048;
constexpr int D = 128;
constexpr int NH = 8;
constexpr int NK = 16;          // num_buckets / 2
constexpr int NB = 32;          // num_buckets
constexpr float EPS = 1e-5f;
constexpr float SCALE = 0.08838834764831845f;  // 1/sqrt(128)

constexpr int MAXN = 192;       // max bucket size (binomial mean 64, sigma ~7.9 -> 12 sigma)
constexpr int KP   = 136;       // Kb row pitch in bf16 elems (128 + 8, keeps 16B alignment)
constexpr int TP   = 200;       // KT/w/Pt row pitch (192 + 8)
constexpr int QSPLIT = 4;       // blocks per bucket (split over query tiles)

typedef __attribute__((ext_vector_type(8))) short bf16x8;
typedef __attribute__((ext_vector_type(4))) float f32x4;

__device__ __forceinline__ ushort f2bf(float f) {
    uint u = __float_as_uint(f);
    u += 0x7FFFu + ((u >> 16) & 1u);     // round-to-nearest-even
    return (ushort)(u >> 16);
}

// ---------------------------------------------------------------------------
// K1: LayerNorm + last-round LSH hash, one WAVE per row, zero barriers.
// Emits: xmb (bf16 xm), bucket id, exact fp32 self-score scale*||xm||^2.
// ---------------------------------------------------------------------------
__global__ __launch_bounds__(256) void ln_hash_kernel(
    const float* __restrict__ x, const float* __restrict__ mask,
    const float* __restrict__ rot, ushort* __restrict__ xmb,
    int* __restrict__ bucket, float* __restrict__ selfp)
{
    const int wave = threadIdx.x >> 6;
    const int lane = threadIdx.x & 63;
    const int row  = blockIdx.x * 4 + wave;       // grid = B*S/4 blocks
    const int b    = row >> 11;                   // row / S

    const float v0 = x[(size_t)row * D + lane];
    const float v1 = x[(size_t)row * D + lane + 64];

    float s = v0 + v1;
    #pragma unroll
    for (int off = 32; off > 0; off >>= 1) s += __shfl_xor(s, off, 64);
    const float mu = s * (1.0f / 128.0f);

    const float c0 = v0 - mu, c1 = v1 - mu;
    float s2 = c0 * c0 + c1 * c1;
    #pragma unroll
    for (int off = 32; off > 0; off >>= 1) s2 += __shfl_xor(s2, off, 64);
    const float rstd = 1.0f / sqrtf(s2 * (1.0f / 128.0f) + EPS);

    const float xn0 = c0 * rstd, xn1 = c1 * rstd;
    const float mk = mask[row];
    xmb[(size_t)row * D + lane]      = f2bf(xn0 * mk);
    xmb[(size_t)row * D + lane + 64] = f2bf(xn1 * mk);

    // projection (last hash round only): rk = sum_d xn[d]*R[b,d,NH-1,k]
    const float* r0 = rot + (((size_t)(b * D + lane)) * NH + (NH - 1)) * NK;
    const float* r1 = rot + (((size_t)(b * D + lane + 64)) * NH + (NH - 1)) * NK;
    float racc[NK];
    #pragma unroll
    for (int k = 0; k < NK; ++k) racc[k] = xn0 * r0[k] + xn1 * r1[k];
    #pragma unroll
    for (int k = 0; k < NK; ++k) {
        float t = racc[k];
        #pragma unroll
        for (int off = 32; off > 0; off >>= 1) t += __shfl_xor(t, off, 64);
        racc[k] = t;
    }

    // argmax over [rot, -rot], first-max semantics
    float best = racc[0]; int bi = 0;
    #pragma unroll
    for (int k = 1; k < NK; ++k) if (racc[k] > best) { best = racc[k]; bi = k; }
    #pragma unroll
    for (int k = 0; k < NK; ++k) if (-racc[k] > best) { best = -racc[k]; bi = k + NK; }

    if (lane == 0) {
        bucket[row] = bi;
        // exact self score: scale * ||xn*mk||^2 = scale * s2 * rstd^2 * mk^2
        selfp[row] = SCALE * s2 * rstd * rstd * mk * mk;
    }
}

// ---------------------------------------------------------------------------
// K2: bucket-centric MFMA attention. Grid = B*NB*QSPLIT = 256 blocks.
// Compaction is DETERMINISTIC + ORDERED (register-chunk scan + prefix sums)
// so the QSPLIT blocks of one bucket agree on idx[] and partition the
// query tiles exactly.
// ---------------------------------------------------------------------------
__global__ __launch_bounds__(256) void attn_kernel(
    const ushort* __restrict__ xmb, const int* __restrict__ bucket,
    const float* __restrict__ selfp, float* __restrict__ out)
{
    const int bg   = blockIdx.x >> 2;     // bucket global id 0..63
    const int qs   = blockIdx.x & 3;      // query-tile split
    const int b    = bg >> 5;
    const int beta = bg & 31;
    const int tid  = threadIdx.x;
    const int lane = tid & 63;
    const int wave = tid >> 6;
    const int col  = lane & 15;           // MFMA n/col index
    const int quad = lane >> 4;           // MFMA k-group

    __shared__ __align__(16) ushort Kb[MAXN * KP];    // keys, row-major bf16
    __shared__ __align__(16) ushort KTb[D * TP];      // keys transposed [d][j]
    __shared__ __align__(16) float  w[16 * TP];       // fp32 scores, one qtile
    __shared__ __align__(16) ushort Pt[16 * TP];      // bf16 exp weights
    __shared__ int   idx[MAXN];
    __shared__ float scratch[256];
    __shared__ float Mrow[16], invrow[16];
    __shared__ int   wsum[4];

    // --- deterministic ordered compaction: thread tid owns rows [tid*8, tid*8+8) ---
    const int base = b * S;
    const int4* bp = (const int4*)(bucket + base);
    const int4 v0 = bp[tid * 2];
    const int4 v1 = bp[tid * 2 + 1];
    int m0 = (v0.x == beta) | ((v0.y == beta) << 1) | ((v0.z == beta) << 2) |
             ((v0.w == beta) << 3) | ((v1.x == beta) << 4) | ((v1.y == beta) << 5) |
             ((v1.z == beta) << 6) | ((v1.w == beta) << 7);
    const int cntl = __popc(m0);

    int inc = cntl;                       // wave-level inclusive scan
    #pragma unroll
    for (int off = 1; off < 64; off <<= 1) {
        const int t = __shfl_up(inc, off, 64);
        if (lane >= off) inc += t;
    }
    if (lane == 63) wsum[wave] = inc;
    __syncthreads();
    int start = inc - cntl;
    #pragma unroll
    for (int wv = 0; wv < 4; ++wv) if (wv < wave) start += wsum[wv];
    const int ntot = wsum[0] + wsum[1] + wsum[2] + wsum[3];
    const int n = min(ntot, MAXN);

    {
        const int t0 = tid * 8;
        int p = start;
        #pragma unroll
        for (int k = 0; k < 8; ++k)
            if ((m0 >> k) & 1) { if (p < MAXN) idx[p] = t0 + k; ++p; }
    }
    __syncthreads();
    if (n == 0) return;
    const int npad32 = (n + 31) & ~31;

    // --- stage keys into LDS (bf16, row-major, padded pitch) ---
    for (int c = tid; c < n * 16; c += 256) {
        const int i = c >> 4, ch = c & 15;
        *(bf16x8*)&Kb[i * KP + ch * 8] =
            *(const bf16x8*)(xmb + (size_t)(base + idx[i]) * D + ch * 8);
    }
    __syncthreads();

    // --- build transpose KT[d][j] = K[j][d]; zero-pad cols [n, npad32) ---
    for (int e = tid; e < n * D; e += 256) {
        const int j = e >> 7, d = e & 127;
        KTb[d * TP + j] = Kb[j * KP + d];
    }
    for (int e = tid; e < D * 32; e += 256) {
        const int d = e >> 5, j = n + (e & 31);
        if (j < npad32) KTb[d * TP + j] = 0;
    }
    for (int e = tid; e < 16 * 32; e += 256) {
        const int r = e >> 5, j = n + (e & 31);
        if (j < npad32) Pt[r * TP + j] = 0;
    }
    __syncthreads();

    // --- query-tile loop (strided over QSPLIT blocks; all blocks agree on idx) ---
    for (int qt = qs; qt * 16 < n; qt += QSPLIT) {
        const int q0 = qt * 16;
        const int rows = min(16, n - q0);

        // Gram: C[i][j] = sum_d K[q0+i][d] * K[J0+j][d], per-wave over key tiles
        for (int kt = wave; kt * 16 < n; kt += 4) {
            const int J0 = kt * 16;
            f32x4 acc = {0.f, 0.f, 0.f, 0.f};
            #pragma unroll
            for (int ks = 0; ks < 4; ++ks) {
                const bf16x8 a = *(const bf16x8*)&Kb[(q0 + col) * KP + quad * 8 + ks * 32];
                const bf16x8 bb = *(const bf16x8*)&Kb[(J0 + col) * KP + quad * 8 + ks * 32];
                acc = __builtin_amdgcn_mfma_f32_16x16x32_bf16(a, bb, acc, 0, 0, 0);
            }
            #pragma unroll
            for (int r = 0; r < 4; ++r)
                w[(quad * 4 + r) * TP + J0 + col] = acc[r] * SCALE;
        }
        __syncthreads();

        // exact diagonal (kills the dominant bf16 error term); ordered idx =>
        // query q0+tid sits at key column q0+tid.
        if (tid < rows)
            w[tid * TP + q0 + tid] = selfp[base + idx[q0 + tid]];
        __syncthreads();

        // softmax: row = tid>>4, 16 threads/row
        {
            const int r = tid >> 4, g = tid & 15;
            float pm = 0.0f;   // the S-n zero scores floor the max at 0
            if (r < rows)
                for (int j = g; j < n; j += 16) pm = fmaxf(pm, w[r * TP + j]);
            scratch[tid] = pm;
            __syncthreads();
            if (tid < 16 && tid < rows) {
                float m = scratch[tid * 16];
                #pragma unroll
                for (int k = 1; k < 16; ++k) m = fmaxf(m, scratch[tid * 16 + k]);
                Mrow[tid] = m;
            }
            __syncthreads();
            float ps = 0.0f;
            if (r < rows) {
                const float M = Mrow[r];
                for (int j = g; j < n; j += 16) {
                    const float e = expf(w[r * TP + j] - M);
                    Pt[r * TP + j] = f2bf(e);
                    ps += e;
                }
            }
            scratch[tid] = ps;
            __syncthreads();
            if (tid < 16 && tid < rows) {
                float ssum = 0.0f;
                #pragma unroll
                for (int k = 0; k < 16; ++k) ssum += scratch[tid * 16 + k];
                ssum += (float)(S - n) * expf(-Mrow[tid]);
                invrow[tid] = 1.0f / ssum;
            }
            __syncthreads();
        }

        // PV: O[i][d] = sum_j P[i][j] * K[j][d], via KT for the B operand
        for (int dt = wave; dt < 8; dt += 4) {
            f32x4 acc = {0.f, 0.f, 0.f, 0.f};
            for (int ks = 0; ks < npad32 / 32; ++ks) {
                const bf16x8 a = *(const bf16x8*)&Pt[col * TP + ks * 32 + quad * 8];
                const bf16x8 bb = *(const bf16x8*)&KTb[(dt * 16 + col) * TP + ks * 32 + quad * 8];
                acc = __builtin_amdgcn_mfma_f32_16x16x32_bf16(a, bb, acc, 0, 0, 0);
            }
            #pragma unroll
            for (int r = 0; r < 4; ++r) {
                const int rr = quad * 4 + r;
                if (rr < rows)
                    out[(size_t)(base + idx[q0 + rr]) * D + dt * 16 + col] =
                        acc[r] * invrow[rr];
            }
        }
        __syncthreads();   // before next qtile reuses w/Pt
    }
}

// ---------------------------------------------------------------------------
extern "C" void kernel_launch(void* const* d_in, const int* in_sizes, int n_in,
                              void* d_out, int out_size, void* d_ws, size_t ws_size,
                              hipStream_t stream) {
    const float* x    = (const float*)d_in[0];   // (B,S,D) fp32
    const float* mask = (const float*)d_in[1];   // (B,S) fp32
    const float* rot  = (const float*)d_in[2];   // (B,D,NH,NK) fp32

    char* ws = (char*)d_ws;
    ushort* xmb  = (ushort*)ws;                  ws += (size_t)B * S * D * sizeof(ushort); // 1 MB
    int*    bkt  = (int*)ws;                     ws += (size_t)B * S * sizeof(int);        // 16 KB
    float*  self = (float*)ws;                                                             // 16 KB
    float*  out  = (float*)d_out;

    ln_hash_kernel<<<B * S / 4, 256, 0, stream>>>(x, mask, rot, xmb, bkt, self);
    attn_kernel<<<B * NB * QSPLIT, 256, 0, stream>>>(xmb, bkt, self, out);
}